// Round 9
// baseline (829.325 us; speedup 1.0000x reference)
//
#include <hip/hip_runtime.h>

#define BB   32
#define SS   512
#define DDIM 512
#define HH   8
#define DFFN 2048
#define MR   (BB*SS)   // 16384 rows

typedef unsigned int   u32;
typedef unsigned short u16;
typedef unsigned char  u8;
typedef __attribute__((ext_vector_type(8))) short bf16x8;
typedef __attribute__((ext_vector_type(4))) float f32x4;

// ---------- bf16 helpers ----------
__device__ __forceinline__ u32 packbf2(float x, float y) {
  u32 ux = __float_as_uint(x), uy = __float_as_uint(y);
  u32 hx = (ux + 0x7FFFu + ((ux >> 16) & 1u)) >> 16;
  u32 hy = (uy + 0x7FFFu + ((uy >> 16) & 1u)) >> 16;
  return hx | (hy << 16);
}
__device__ __forceinline__ u16 pack1bf(float x) {
  u32 u = __float_as_uint(x);
  return (u16)((u + 0x7FFFu + ((u >> 16) & 1u)) >> 16);
}

__device__ __forceinline__ float redsum2(float v) {
  v += __shfl_xor(v, 16, 64);
  v += __shfl_xor(v, 32, 64);
  return v;
}

// exp without max-subtraction: clamp keeps 512*e^80 < f32 max. Scores here are
// O(10); values above 80 are softmax-saturated anyway (matches ref within tol).
__device__ __forceinline__ float expc(float x) { return __expf(fminf(x, 80.f)); }

// ---------- flat f32 -> bf16 pack ----------
__global__ __launch_bounds__(256) void pack_flat(const float* __restrict__ in,
                                                 u16* __restrict__ out) {
  size_t i = ((size_t)blockIdx.x * 256 + threadIdx.x) * 8;
  float4 a = *(const float4*)(in + i);
  float4 b = *(const float4*)(in + i + 4);
  uint4 o;
  o.x = packbf2(a.x, a.y); o.y = packbf2(a.z, a.w);
  o.z = packbf2(b.x, b.y); o.w = packbf2(b.z, b.w);
  *(uint4*)(out + i) = o;
}

// ---------- weight transpose-pack: f32 [K,N] -> bf16 [N,K], gridDim.z = layers ----------
__global__ __launch_bounds__(256) void pack_w_t(const float* __restrict__ in,
                                                u16* __restrict__ out, int K, int N) {
  __shared__ float tile[64][65];
  const int t  = threadIdx.x;
  const int n0 = blockIdx.x * 64, k0 = blockIdx.y * 64;
  in  += (size_t)blockIdx.z * K * N;
  out += (size_t)blockIdx.z * N * K;
  #pragma unroll
  for (int it = 0; it < 4; ++it) {
    int idx = it * 256 + t;
    int kk = idx >> 4, n4 = idx & 15;
    float4 v = *(const float4*)(in + (size_t)(k0 + kk) * N + n0 + n4 * 4);
    tile[kk][n4*4+0] = v.x; tile[kk][n4*4+1] = v.y;
    tile[kk][n4*4+2] = v.z; tile[kk][n4*4+3] = v.w;
  }
  __syncthreads();
  #pragma unroll
  for (int it = 0; it < 4; ++it) {
    int idx = it * 256 + t;
    int nn = idx >> 4, g = idx & 15;
    uint2 o;
    o.x = packbf2(tile[g*4+0][nn], tile[g*4+1][nn]);
    o.y = packbf2(tile[g*4+2][nn], tile[g*4+3][nn]);
    *(uint2*)(out + (size_t)(n0 + nn) * K + k0 + g * 4) = o;
  }
}

// ---------- V transpose: V[b,s,h,d] (bf16) -> VT[bh][64 d][512 s] (bf16) ----------
__global__ __launch_bounds__(256) void vt_pack(const u16* __restrict__ v,
                                               u16* __restrict__ vt) {
  __shared__ u16 tile[128][72];
  const int t  = threadIdx.x;
  const int bh = blockIdx.x, b = bh >> 3, h = bh & 7;
  const int s0 = blockIdx.y * 128;
  const u16* src = v + (size_t)b * SS * DDIM + (size_t)h * 64;
  #pragma unroll
  for (int it = 0; it < 4; ++it) {
    int id = it * 256 + t;
    int si = id >> 3, dseg = id & 7;
    uint4 w = *(const uint4*)(src + (size_t)(s0 + si) * DDIM + dseg * 8);
    *(uint4*)&tile[si][dseg * 8] = w;
  }
  __syncthreads();
  u16* dst = vt + (size_t)bh * 64 * SS + s0;
  #pragma unroll
  for (int it = 0; it < 4; ++it) {
    int id = it * 256 + t;
    int d = id >> 4, sc = id & 15;
    u16 buf[8];
    #pragma unroll
    for (int j = 0; j < 8; ++j) buf[j] = tile[sc * 8 + j][d];
    *(uint4*)(dst + (size_t)d * SS + sc * 8) = *(uint4*)buf;
  }
}

// ---------- 256x256 8-phase bf16 MFMA GEMM (m201-style port, plain HIP) ----------
__global__ __launch_bounds__(512, 2) void gemm8(
    const u16* __restrict__ Aa, const u16* __restrict__ Ab, int lda,
    const u16* __restrict__ Ba, const u16* __restrict__ Bb, int ldb,
    const float* __restrict__ biasa, const float* __restrict__ biasb,
    float* __restrict__ outFa, float* __restrict__ outFb,
    u16* __restrict__ outBa, u16* __restrict__ outBb,
    int ldc, int Kz, int relu)
{
  __shared__ __align__(16) u8 lds[131072];

  const int z = blockIdx.z;
  const u16* A    = z ? Ab : Aa;
  const u16* Bt   = z ? Bb : Ba;
  const float* bias = z ? biasb : biasa;
  float* outF = z ? outFb : outFa;
  u16*   outB = z ? outBb : outBa;

  const int nwg  = gridDim.x * gridDim.y;
  const int orig = blockIdx.y * gridDim.x + blockIdx.x;
  const int q8   = nwg >> 3, r8 = nwg & 7;
  const int xcd  = orig & 7, idx8 = orig >> 3;
  const int wg   = (xcd < r8 ? xcd * (q8 + 1) : r8 * (q8 + 1) + (xcd - r8) * q8) + idx8;
  const int bx   = wg % gridDim.x, by = wg / gridDim.x;
  const int row0 = by * 256, col0 = bx * 256;

  const int t    = threadIdx.x;
  const int lane = t & 63, wid = t >> 6;
  const int wm   = wid >> 2, wn = wid & 3;
  const int rl   = lane & 15, kg = lane >> 4;

  const int NT = Kz >> 6;

  f32x4 acc[8][4] = {};

  auto stageA = [&](int buf, int h, int kt) {
    #pragma unroll
    for (int l = 0; l < 2; ++l) {
      int s  = (l * 512 + t) >> 3;
      int kb = ((lane & 7) * 16) ^ ((s & 7) << 4);
      int row = row0 + ((s >> 6) * 128) + h * 64 + (s & 63);
      const u8* src = (const u8*)A + (size_t)row * lda * 2 + (size_t)kt * 128 + kb;
      u8* dst = lds + buf * 65536 + h * 16384 + (l * 512 + wid * 64) * 16;
      __builtin_amdgcn_global_load_lds(
          (const __attribute__((address_space(1))) u32*)src,
          (__attribute__((address_space(3))) u32*)dst, 16, 0, 0);
    }
  };
  auto stageB = [&](int buf, int h, int kt) {
    #pragma unroll
    for (int l = 0; l < 2; ++l) {
      int s  = (l * 512 + t) >> 3;
      int kb = ((lane & 7) * 16) ^ ((s & 7) << 4);
      int col = col0 + ((s >> 5) * 64) + h * 32 + (s & 31);
      const u8* src = (const u8*)Bt + (size_t)col * ldb * 2 + (size_t)kt * 128 + kb;
      u8* dst = lds + buf * 65536 + 32768 + h * 16384 + (l * 512 + wid * 64) * 16;
      __builtin_amdgcn_global_load_lds(
          (const __attribute__((address_space(1))) u32*)src,
          (__attribute__((address_space(3))) u32*)dst, 16, 0, 0);
    }
  };

  auto rdA = [&](int buf, int mh, int m, int ks) -> bf16x8 {
    int s = wm * 64 + m * 16 + rl;
    int off = buf * 65536 + mh * 16384 + s * 128 + (((ks * 32 + kg * 8) * 2) ^ ((s & 7) << 4));
    return *(const bf16x8*)(lds + off);
  };
  auto rdB = [&](int buf, int nh, int n, int ks) -> bf16x8 {
    int s = wn * 32 + n * 16 + rl;
    int off = buf * 65536 + 32768 + nh * 16384 + s * 128 + (((ks * 32 + kg * 8) * 2) ^ ((s & 7) << 4));
    return *(const bf16x8*)(lds + off);
  };

#define GBAR asm volatile("s_barrier" ::: "memory")
#define VMW4 asm volatile("s_waitcnt vmcnt(4)" ::: "memory")

#define PHASE(BUF, MH, NH, STAGECODE, DOVM) do {                               \
    bf16x8 af_[4][2], bf_[2][2];                                               \
    _Pragma("unroll") for (int m_ = 0; m_ < 4; ++m_)                           \
      _Pragma("unroll") for (int k_ = 0; k_ < 2; ++k_)                         \
        af_[m_][k_] = rdA(BUF, MH, m_, k_);                                    \
    _Pragma("unroll") for (int n_ = 0; n_ < 2; ++n_)                           \
      _Pragma("unroll") for (int k_ = 0; k_ < 2; ++k_)                         \
        bf_[n_][k_] = rdB(BUF, NH, n_, k_);                                    \
    STAGECODE;                                                                 \
    if (DOVM) VMW4;                                                            \
    GBAR;                                                                      \
    __builtin_amdgcn_s_setprio(1);                                             \
    _Pragma("unroll") for (int m_ = 0; m_ < 4; ++m_)                           \
      _Pragma("unroll") for (int n_ = 0; n_ < 2; ++n_) {                       \
        acc[(MH)*4+m_][(NH)*2+n_] = __builtin_amdgcn_mfma_f32_16x16x32_bf16(   \
            af_[m_][0], bf_[n_][0], acc[(MH)*4+m_][(NH)*2+n_], 0, 0, 0);       \
        acc[(MH)*4+m_][(NH)*2+n_] = __builtin_amdgcn_mfma_f32_16x16x32_bf16(   \
            af_[m_][1], bf_[n_][1], acc[(MH)*4+m_][(NH)*2+n_], 0, 0, 0);       \
      }                                                                        \
    __builtin_amdgcn_s_setprio(0);                                             \
    GBAR;                                                                      \
  } while (0)

  stageA(0, 0, 0); stageB(0, 0, 0); stageA(0, 1, 0); stageB(0, 1, 0);
  stageA(1, 0, 1); stageB(1, 0, 1);
  VMW4; GBAR;

  for (int i = 0; i < (NT >> 1); ++i) {
    const int T1 = 2 * i + 1;
    int T2 = 2 * i + 2; if (T2 >= NT) T2 -= NT;
    int T3 = 2 * i + 3; if (T3 >= NT) T3 -= NT;
    PHASE(0, 0, 0, stageA(1, 1, T1), 0);
    PHASE(0, 0, 1, stageB(1, 1, T1), 0);
    PHASE(0, 1, 0, stageA(0, 0, T2), 0);
    PHASE(0, 1, 1, stageB(0, 0, T2), 1);
    PHASE(1, 0, 0, stageA(0, 1, T2), 0);
    PHASE(1, 0, 1, stageB(0, 1, T2), 0);
    PHASE(1, 1, 0, stageA(1, 0, T3), 0);
    PHASE(1, 1, 1, stageB(1, 0, T3), 1);
  }
#undef PHASE
#undef GBAR
#undef VMW4

  #pragma unroll
  for (int M = 0; M < 8; ++M) {
    #pragma unroll
    for (int N2 = 0; N2 < 4; ++N2) {
      const int col = col0 + wn * 64 + N2 * 16 + rl;
      const float bs = bias ? bias[col] : 0.f;
      #pragma unroll
      for (int q = 0; q < 4; ++q) {
        const int row = row0 + wm * 128 + M * 16 + kg * 4 + q;
        float v = acc[M][N2][q] + bs;
        if (relu) v = fmaxf(v, 0.f);
        if (outF) outF[(size_t)row * ldc + col] = v;
        if (outB) outB[(size_t)row * ldc + col] = pack1bf(v);
      }
    }
  }
}

// ---------- MFMA attention, 2-pass streamed, no-max softmax, V^T from global ----------
// Grid = BB*HH*2: each (b,h) split into 2 blocks (z) of 8 waves. Wave handles
// row-tiles {v, 31-v}, v = z*8+wid (cost-balanced causal). LDS = K only (64KB)
// + P chunk buffers (8KB) = 72KB -> 2 blocks/CU = 4 waves/SIMD (r8: attn was
// VALU-bound at 59% busy with only 2 waves/SIMD). V^T precomputed in global
// (vt_pack), PV B-frags read straight from L2 (64KB/head, ~32x reuse).
__global__ __launch_bounds__(512, 2) void attn_mfma(
    const u16* __restrict__ qk, const u16* __restrict__ vt,
    const float* __restrict__ gam, u16* __restrict__ out,
    int mask_excl, int zero_pad)
{
  __shared__ __align__(16) u8 kSb[65536];  // K/Q rows [512][64] bf16, byte ^= (row&7)<<4
  __shared__ __align__(16) u8 pChb[8192];  // per-wave 1KB P chunk buffers

  const int t    = threadIdx.x;
  const int lane = t & 63, wid = t >> 6;
  const int ql   = lane & 15, g = lane >> 4;
  const int bh   = blockIdx.x >> 1, z = blockIdx.x & 1;
  const int b    = bh >> 3, h = bh & 7;
  const size_t base = (size_t)b * SS * DDIM + (size_t)h * 64;
  const u16* vtb = vt + (size_t)bh * 64 * SS;

  float gv = gam[h];
  float sp = (gv > 0.f) ? (gv + log1pf(__expf(-gv))) : log1pf(__expf(gv));
  const float gamma = -sp;

  for (int it = 0; it < 8; ++it) {
    int idx = it * 512 + t;
    int j = idx >> 3, u = idx & 7;
    uint4 w = *(const uint4*)(qk + base + (size_t)j * DDIM + u * 8);
    *(uint4*)(kSb + ((j * 128 + u * 16) ^ ((j & 7) << 4))) = w;
  }
  __syncthreads();

  bool vm[4];
  #pragma unroll
  for (int rg = 0; rg < 4; ++rg) {
    int kl = 4 * g + rg;
    vm[rg] = mask_excl ? (kl < ql) : (kl <= ql);
  }

  u8* pB = pChb + wid * 1024;
  const int swp = (ql & 3) << 4;

  #pragma unroll
  for (int ri = 0; ri < 2; ++ri) {
    const int v_ = z * 8 + wid;
    const int rs = __builtin_amdgcn_readfirstlane(ri ? (31 - v_) : v_);
    const int i0 = rs * 16;

    const int qrow = i0 + ql;
    const int qsw  = (qrow & 7) << 4;
    bf16x8 qf0 = *(const bf16x8*)(kSb + ((qrow * 128      + g * 16) ^ qsw));
    bf16x8 qf1 = *(const bf16x8*)(kSb + ((qrow * 128 + 64 + g * 16) ^ qsw));

    // ---- pass 1: S1 only (no max tracking) ----
    float S1l = 0.f;
    #pragma unroll
    for (int kt = 0; kt < 32; ++kt) {
      if (kt <= rs) {
        const bool dg = (kt == rs);
        const int krow = kt * 16 + ql;
        const int ksw  = (krow & 7) << 4;
        bf16x8 ka0 = *(const bf16x8*)(kSb + ((krow * 128      + g * 16) ^ ksw));
        bf16x8 ka1 = *(const bf16x8*)(kSb + ((krow * 128 + 64 + g * 16) ^ ksw));
        f32x4 dv = {};
        dv = __builtin_amdgcn_mfma_f32_16x16x32_bf16(ka0, qf0, dv, 0, 0, 0);
        dv = __builtin_amdgcn_mfma_f32_16x16x32_bf16(ka1, qf1, dv, 0, 0, 0);
        float e0 = (!dg || vm[0]) ? expc(dv[0] * 0.125f) : 0.f;
        float e1 = (!dg || vm[1]) ? expc(dv[1] * 0.125f) : 0.f;
        float e2 = (!dg || vm[2]) ? expc(dv[2] * 0.125f) : 0.f;
        float e3 = (!dg || vm[3]) ? expc(dv[3] * 0.125f) : 0.f;
        S1l += (e0 + e1) + (e2 + e3);
      }
    }
    const float S1   = redsum2(S1l);
    const float inv1 = (S1 > 0.f) ? (1.f / S1) : 0.f;

    // ---- pass 2: streamed recompute -> cumsum -> rescore -> PV ----
    f32x4 oacc[4] = {};
    float cbase = 0.f, S2l = 0.f;
    const float qlf = (float)(i0 + ql);

    auto subkt = [&](int kt, bool dg, u32& wA, u32& wB) {
      const int krow = kt * 16 + ql;
      const int ksw  = (krow & 7) << 4;
      bf16x8 ka0 = *(const bf16x8*)(kSb + ((krow * 128      + g * 16) ^ ksw));
      bf16x8 ka1 = *(const bf16x8*)(kSb + ((krow * 128 + 64 + g * 16) ^ ksw));
      f32x4 dv = {};
      dv = __builtin_amdgcn_mfma_f32_16x16x32_bf16(ka0, qf0, dv, 0, 0, 0);
      dv = __builtin_amdgcn_mfma_f32_16x16x32_bf16(ka1, qf1, dv, 0, 0, 0);
      float sv[4];
      sv[0] = dv[0] * 0.125f; sv[1] = dv[1] * 0.125f;
      sv[2] = dv[2] * 0.125f; sv[3] = dv[3] * 0.125f;
      const bool v0 = !dg || vm[0], v1 = !dg || vm[1];
      const bool v2 = !dg || vm[2], v3 = !dg || vm[3];
      float e0 = v0 ? expc(sv[0]) : 0.f;
      float e1 = v1 ? expc(sv[1]) : 0.f;
      float e2 = v2 ? expc(sv[2]) : 0.f;
      float e3 = v3 ? expc(sv[3]) : 0.f;
      float p0 = e0, p1 = p0 + e1, p2 = p1 + e2, p3 = p2 + e3;
      float a16 = __shfl_up(p3, 16, 64);
      float a32 = __shfl_up(p3, 32, 64);
      float a48 = __shfl_up(p3, 48, 64);
      float gp = (g >= 1 ? a16 : 0.f) + (g >= 2 ? a32 : 0.f) + (g >= 3 ? a48 : 0.f);
      float tt = __shfl(gp + p3, ql + 48, 64);
      const float pbase = cbase + gp;
      const float pf = qlf - (float)(kt * 16 + 4 * g);
      float ipr[4] = {p0, p1, p2, p3};
      bool  vv[4]  = {v0, v1, v2, v3};
      float q2[4];
      #pragma unroll
      for (int rg = 0; rg < 4; ++rg) {
        float rem  = fmaxf((S1 - (pbase + ipr[rg])) * inv1, 0.f);
        float pos  = pf - (float)rg;
        float dist = sqrtf(fmaxf(rem * pos, 0.f));
        float eff  = fmaxf(__expf(gamma * dist), 1e-5f);
        float ee   = vv[rg] ? expc(sv[rg] * eff) : 0.f;
        q2[rg] = ee;
        S2l += ee;
      }
      wA = packbf2(q2[0], q2[1]);
      wB = packbf2(q2[2], q2[3]);
      cbase += tt;
    };

    #pragma unroll
    for (int c = 0; c < 16; ++c) {
      if (2 * c <= rs) {
        u32 w0 = 0, w1 = 0, w2 = 0, w3 = 0;
        subkt(2 * c, (2 * c == rs), w0, w1);
        if (2 * c + 1 <= rs) subkt(2 * c + 1, (2 * c + 1 == rs), w2, w3);
        *(u32*)(pB + ((ql * 64 +      8 * g    ) ^ swp)) = w0;
        *(u32*)(pB + ((ql * 64 +      8 * g + 4) ^ swp)) = w1;
        *(u32*)(pB + ((ql * 64 + 32 + 8 * g    ) ^ swp)) = w2;
        *(u32*)(pB + ((ql * 64 + 32 + 8 * g + 4) ^ swp)) = w3;
        bf16x8 pa = *(const bf16x8*)(pB + ((ql * 64 + 16 * g) ^ swp));
        #pragma unroll
        for (int n = 0; n < 4; ++n) {
          // V^T B-frag from global (L2-resident): d = n*16+ql, k = 32c+8g..+8
          bf16x8 vb = *(const bf16x8*)(vtb + (size_t)(n * 16 + ql) * SS + 32 * c + 8 * g);
          oacc[n] = __builtin_amdgcn_mfma_f32_16x16x32_bf16(pa, vb, oacc[n], 0, 0, 0);
        }
      }
    }

    const float S2   = redsum2(S2l);
    const float inv2 = 1.f / fmaxf(S2, 1e-30f);
    float i2[4];
    #pragma unroll
    for (int rg = 0; rg < 4; ++rg) i2[rg] = __shfl(inv2, 4 * g + rg, 64);

    #pragma unroll
    for (int n = 0; n < 4; ++n) {
      #pragma unroll
      for (int rg = 0; rg < 4; ++rg) {
        const int qo = i0 + 4 * g + rg;
        float val = oacc[n][rg] * i2[rg];
        if (zero_pad && qo == 0) val = 0.f;
        out[base + (size_t)qo * DDIM + n * 16 + ql] = pack1bf(val);
      }
    }
  }
}

// ---------- fused residual + LayerNorm: out = LN(a + b [+ c]) ----------
__global__ __launch_bounds__(256) void ln_kernel(
    const float* __restrict__ a, const float* __restrict__ bsrc,
    const float* __restrict__ csrc,
    const float* __restrict__ g, const float* __restrict__ be,
    float* __restrict__ outF, u16* __restrict__ outB)
{
  const int lane = threadIdx.x & 63, w = threadIdx.x >> 6;
  const size_t row = (size_t)blockIdx.x * 4 + w;
  const float* pa = a    + row * DDIM;
  const float* pb = bsrc + row * DDIM;
  const float* pc = csrc ? csrc + row * DDIM : nullptr;
  float v[8];
  float sum = 0.f;
  #pragma unroll
  for (int c = 0; c < 2; ++c) {
    float4 va = *(const float4*)(pa + c * 256 + lane * 4);
    float4 vb = *(const float4*)(pb + c * 256 + lane * 4);
    v[c*4+0] = va.x + vb.x; v[c*4+1] = va.y + vb.y;
    v[c*4+2] = va.z + vb.z; v[c*4+3] = va.w + vb.w;
    if (pc) {
      float4 vc = *(const float4*)(pc + c * 256 + lane * 4);
      v[c*4+0] += vc.x; v[c*4+1] += vc.y; v[c*4+2] += vc.z; v[c*4+3] += vc.w;
    }
    sum += v[c*4+0] + v[c*4+1] + v[c*4+2] + v[c*4+3];
  }
  #pragma unroll
  for (int off = 32; off > 0; off >>= 1) sum += __shfl_xor(sum, off, 64);
  const float mean = sum * (1.f / 512.f);
  float var = 0.f;
  #pragma unroll
  for (int k = 0; k < 8; ++k) { float dd = v[k] - mean; var = fmaf(dd, dd, var); }
  #pragma unroll
  for (int off = 32; off > 0; off >>= 1) var += __shfl_xor(var, off, 64);
  var *= (1.f / 512.f);
  const float inv = rsqrtf(var + 1e-5f);
  #pragma unroll
  for (int c = 0; c < 2; ++c) {
    float4 gg = *(const float4*)(g  + c * 256 + lane * 4);
    float4 bb = *(const float4*)(be + c * 256 + lane * 4);
    float4 o;
    o.x = (v[c*4+0] - mean) * inv * gg.x + bb.x;
    o.y = (v[c*4+1] - mean) * inv * gg.y + bb.y;
    o.z = (v[c*4+2] - mean) * inv * gg.z + bb.z;
    o.w = (v[c*4+3] - mean) * inv * gg.w + bb.w;
    const size_t off4 = row * DDIM + c * 256 + lane * 4;
    if (outF) *(float4*)(outF + off4) = o;
    if (outB) {
      uint2 p;
      p.x = packbf2(o.x, o.y); p.y = packbf2(o.z, o.w);
      *(uint2*)(outB + off4) = p;
    }
  }
}

// ---------- orchestration ----------
extern "C" void kernel_launch(void* const* d_in, const int* in_sizes, int n_in,
                              void* d_out, int out_size, void* d_ws, size_t ws_size,
                              hipStream_t stream) {
  const float* qe  = (const float*)d_in[0];
  const float* qa  = (const float*)d_in[1];
  const float* Wk  = (const float*)d_in[2];
  const float* bk  = (const float*)d_in[3];
  const float* Wv  = (const float*)d_in[4];
  const float* bv  = (const float*)d_in[5];
  const float* Wo  = (const float*)d_in[6];
  const float* bo  = (const float*)d_in[7];
  const float* gm  = (const float*)d_in[8];
  const float* l1g = (const float*)d_in[9];
  const float* l1b = (const float*)d_in[10];
  const float* W1  = (const float*)d_in[11];
  const float* b1  = (const float*)d_in[12];
  const float* W2  = (const float*)d_in[13];
  const float* b2  = (const float*)d_in[14];
  const float* l2g = (const float*)d_in[15];
  const float* l2b = (const float*)d_in[16];

  char* ws = (char*)d_ws;
  u16* WT = (u16*)ws;                              // 17.3 MB packed weights
  u16* A0 = (u16*)(ws + ((size_t)18  << 20));      // 16 MiB bf16 act slots
  u16* A1 = (u16*)(ws + ((size_t)34  << 20));
  u16* A2 = (u16*)(ws + ((size_t)50  << 20));
  u16* A3 = (u16*)(ws + ((size_t)66  << 20));
  float* F0 = (float*)(ws + ((size_t)82  << 20));  // 32 MiB f32 slot
  float* F1 = (float*)(ws + ((size_t)114 << 20));  // 32 MiB f32 slot
  u16* Amid = (u16*)(ws + ((size_t)146 << 20));    // 64 MiB FFN mid
  float* PWo = (float*)Amid;                        // Wo split-K partial (disjoint lifetime)
  float* PW2 = (float*)A2;                          // W2 split-K partial (A2 dead there)
  u16* VT   = (u16*)F0;                             // V^T (F0 dead during attention)

  u16* WkT = WT;                    // [L][512][512]
  u16* WvT = WT + (size_t)3 * 262144;
  u16* WoT = WT + (size_t)6 * 262144;
  u16* W1T = WT + (size_t)9 * 262144;              // [L][2048][512]
  u16* W2T = W1T + (size_t)3 * 1048576;            // [L][512][2048]

  pack_w_t<<<dim3(8, 8, 3),  256, 0, stream>>>(Wk, WkT, 512, 512);
  pack_w_t<<<dim3(8, 8, 3),  256, 0, stream>>>(Wv, WvT, 512, 512);
  pack_w_t<<<dim3(8, 8, 3),  256, 0, stream>>>(Wo, WoT, 512, 512);
  pack_w_t<<<dim3(32, 8, 3), 256, 0, stream>>>(W1, W1T, 512, 2048);
  pack_w_t<<<dim3(8, 32, 3), 256, 0, stream>>>(W2, W2T, 2048, 512);
  pack_flat<<<4096, 256, 0, stream>>>(qa, A0);
  pack_flat<<<4096, 256, 0, stream>>>(qe, A1);

  auto g8 = [&](const u16* Aa, const u16* Ab, int lda,
                const u16* Ba, const u16* Bb, int ldb,
                const float* ba, const float* bb,
                float* oFa, float* oFb, u16* oBa, u16* oBb,
                int ldc, int M, int N, int Kz, int relu, int nz) {
    gemm8<<<dim3(N / 256, M / 256, nz), 512, 0, stream>>>(
        Aa, Ab, lda, Ba, Bb, ldb, ba, bb, oFa, oFb, oBa, oBb, ldc, Kz, relu);
  };

  auto layer = [&](int li, const u16* qbf, const float* qf32, const u16* vbf,
                   int excl, int zp, int pos,
                   float* lnF, u16* lnB, float* y2F, u16* y2B) {
    const float* bk_l = bk + (size_t)li * DDIM;
    const float* bv_l = bv + (size_t)li * DDIM;
    const float* bo_l = bo + (size_t)li * DDIM;
    const float* gm_l = gm + (size_t)li * HH;
    const float* g1   = l1g + (size_t)li * DDIM;
    const float* be1  = l1b + (size_t)li * DDIM;
    const float* g2   = l2g + (size_t)li * DDIM;
    const float* be2  = l2b + (size_t)li * DDIM;
    const float* b1_l = b1 + (size_t)li * DFFN;
    const float* b2_l = b2 + (size_t)li * DDIM;
    const u16* WkT_l = WkT + (size_t)li * 262144;
    const u16* WvT_l = WvT + (size_t)li * 262144;
    const u16* WoT_l = WoT + (size_t)li * 262144;
    const u16* W1T_l = W1T + (size_t)li * 1048576;
    const u16* W2T_l = W2T + (size_t)li * 1048576;

    // fused qk + v projections (z-batched)
    g8(qbf, vbf, 512, WkT_l, WvT_l, 512, bk_l, bv_l,
       nullptr, nullptr, A2, A3, 512, MR, 512, 512, 0, 2);
    // V -> V^T in global (F0 region, dead here)
    vt_pack<<<dim3(BB * HH, 4), 256, 0, stream>>>(A3, VT);
    attn_mfma<<<BB * HH * 2, 512, 0, stream>>>(A2, VT, gm_l, A3, excl, zp);
    // Wo: split-K (z0: k<256 +bias -> F0; z1: k>=256 -> PWo)
    g8(A3, A3 + 256, 512, WoT_l, WoT_l + 256, 512, bo_l, nullptr,
       F0, PWo, nullptr, nullptr, 512, MR, 512, 256, 0, 2);
    ln_kernel<<<MR / 4, 256, 0, stream>>>(qf32, F0, PWo, g1, be1, lnF, lnB);
    if (pos) {
      g8(lnB, nullptr, 512, W1T_l, nullptr, 512, b1_l, nullptr,
         nullptr, nullptr, Amid, nullptr, 2048, MR, 2048, 512, 1, 1);
      g8(Amid, Amid + 1024, 2048, W2T_l, W2T_l + 1024, 2048, b2_l, nullptr,
         F0, PW2, nullptr, nullptr, 512, MR, 512, 1024, 0, 2);
      ln_kernel<<<MR / 4, 256, 0, stream>>>(lnF, F0, PW2, g2, be2, y2F, y2B);
    }
  };

  // layer 0: self-attn on qa, incl mask, FFN -> y1 (bf16 in A0)
  layer(0, A0, qa, A0, 0, 0, 1, F1, A2, nullptr, A0);
  // layer 1: self-attn on qe, incl mask, no FFN -> x1 (f32 F1, bf16 A1)
  layer(1, A1, qe, A1, 0, 0, 0, F1, A1, nullptr, nullptr);
  // layer 2: cross-attn (q = x1, values = y1), strict mask, zero_pad, FFN -> d_out
  layer(2, A1, F1, A0, 1, 1, 1, F1, A1, (float*)d_out, nullptr);
}

// Round 10
// 699.958 us; speedup vs baseline: 1.1848x; 1.1848x over previous
//
#include <hip/hip_runtime.h>

#define BB   32
#define SS   512
#define DDIM 512
#define HH   8
#define DFFN 2048
#define MR   (BB*SS)   // 16384 rows

typedef unsigned int   u32;
typedef unsigned short u16;
typedef unsigned char  u8;
typedef __attribute__((ext_vector_type(8))) short bf16x8;
typedef __attribute__((ext_vector_type(4))) float f32x4;

// ---------- bf16 helpers ----------
__device__ __forceinline__ u32 packbf2(float x, float y) {
  u32 ux = __float_as_uint(x), uy = __float_as_uint(y);
  u32 hx = (ux + 0x7FFFu + ((ux >> 16) & 1u)) >> 16;
  u32 hy = (uy + 0x7FFFu + ((uy >> 16) & 1u)) >> 16;
  return hx | (hy << 16);
}
__device__ __forceinline__ u16 pack1bf(float x) {
  u32 u = __float_as_uint(x);
  return (u16)((u + 0x7FFFu + ((u >> 16) & 1u)) >> 16);
}

__device__ __forceinline__ float redsum2(float v) {
  v += __shfl_xor(v, 16, 64);
  v += __shfl_xor(v, 32, 64);
  return v;
}

// exp without max-subtraction: clamp keeps 512*e^80 < f32 max (r9-proven:
// absmax identical to max-tracked version; scores are O(10)).
__device__ __forceinline__ float expc(float x) { return __expf(fminf(x, 80.f)); }

// ---------- flat f32 -> bf16 pack ----------
__global__ __launch_bounds__(256) void pack_flat(const float* __restrict__ in,
                                                 u16* __restrict__ out) {
  size_t i = ((size_t)blockIdx.x * 256 + threadIdx.x) * 8;
  float4 a = *(const float4*)(in + i);
  float4 b = *(const float4*)(in + i + 4);
  uint4 o;
  o.x = packbf2(a.x, a.y); o.y = packbf2(a.z, a.w);
  o.z = packbf2(b.x, b.y); o.w = packbf2(b.z, b.w);
  *(uint4*)(out + i) = o;
}

// ---------- weight transpose-pack: f32 [K,N] -> bf16 [N,K], gridDim.z = layers ----------
__global__ __launch_bounds__(256) void pack_w_t(const float* __restrict__ in,
                                                u16* __restrict__ out, int K, int N) {
  __shared__ float tile[64][65];
  const int t  = threadIdx.x;
  const int n0 = blockIdx.x * 64, k0 = blockIdx.y * 64;
  in  += (size_t)blockIdx.z * K * N;
  out += (size_t)blockIdx.z * N * K;
  #pragma unroll
  for (int it = 0; it < 4; ++it) {
    int idx = it * 256 + t;
    int kk = idx >> 4, n4 = idx & 15;
    float4 v = *(const float4*)(in + (size_t)(k0 + kk) * N + n0 + n4 * 4);
    tile[kk][n4*4+0] = v.x; tile[kk][n4*4+1] = v.y;
    tile[kk][n4*4+2] = v.z; tile[kk][n4*4+3] = v.w;
  }
  __syncthreads();
  #pragma unroll
  for (int it = 0; it < 4; ++it) {
    int idx = it * 256 + t;
    int nn = idx >> 4, g = idx & 15;
    uint2 o;
    o.x = packbf2(tile[g*4+0][nn], tile[g*4+1][nn]);
    o.y = packbf2(tile[g*4+2][nn], tile[g*4+3][nn]);
    *(uint2*)(out + (size_t)(n0 + nn) * K + k0 + g * 4) = o;
  }
}

// ---------- 256x256 8-phase bf16 MFMA GEMM (m201-style port, plain HIP) ----------
// Per-z output scale sca/scb (folds the attention 1/sqrt(dk) into the QK proj).
__global__ __launch_bounds__(512, 2) void gemm8(
    const u16* __restrict__ Aa, const u16* __restrict__ Ab, int lda,
    const u16* __restrict__ Ba, const u16* __restrict__ Bb, int ldb,
    const float* __restrict__ biasa, const float* __restrict__ biasb,
    float* __restrict__ outFa, float* __restrict__ outFb,
    u16* __restrict__ outBa, u16* __restrict__ outBb,
    int ldc, int Kz, int relu, float sca, float scb)
{
  __shared__ __align__(16) u8 lds[131072];

  const int z = blockIdx.z;
  const u16* A    = z ? Ab : Aa;
  const u16* Bt   = z ? Bb : Ba;
  const float* bias = z ? biasb : biasa;
  float* outF = z ? outFb : outFa;
  u16*   outB = z ? outBb : outBa;
  const float sc = z ? scb : sca;

  const int nwg  = gridDim.x * gridDim.y;
  const int orig = blockIdx.y * gridDim.x + blockIdx.x;
  const int q8   = nwg >> 3, r8 = nwg & 7;
  const int xcd  = orig & 7, idx8 = orig >> 3;
  const int wg   = (xcd < r8 ? xcd * (q8 + 1) : r8 * (q8 + 1) + (xcd - r8) * q8) + idx8;
  const int bx   = wg % gridDim.x, by = wg / gridDim.x;
  const int row0 = by * 256, col0 = bx * 256;

  const int t    = threadIdx.x;
  const int lane = t & 63, wid = t >> 6;
  const int wm   = wid >> 2, wn = wid & 3;
  const int rl   = lane & 15, kg = lane >> 4;

  const int NT = Kz >> 6;

  f32x4 acc[8][4] = {};

  auto stageA = [&](int buf, int h, int kt) {
    #pragma unroll
    for (int l = 0; l < 2; ++l) {
      int s  = (l * 512 + t) >> 3;
      int kb = ((lane & 7) * 16) ^ ((s & 7) << 4);
      int row = row0 + ((s >> 6) * 128) + h * 64 + (s & 63);
      const u8* src = (const u8*)A + (size_t)row * lda * 2 + (size_t)kt * 128 + kb;
      u8* dst = lds + buf * 65536 + h * 16384 + (l * 512 + wid * 64) * 16;
      __builtin_amdgcn_global_load_lds(
          (const __attribute__((address_space(1))) u32*)src,
          (__attribute__((address_space(3))) u32*)dst, 16, 0, 0);
    }
  };
  auto stageB = [&](int buf, int h, int kt) {
    #pragma unroll
    for (int l = 0; l < 2; ++l) {
      int s  = (l * 512 + t) >> 3;
      int kb = ((lane & 7) * 16) ^ ((s & 7) << 4);
      int col = col0 + ((s >> 5) * 64) + h * 32 + (s & 31);
      const u8* src = (const u8*)Bt + (size_t)col * ldb * 2 + (size_t)kt * 128 + kb;
      u8* dst = lds + buf * 65536 + 32768 + h * 16384 + (l * 512 + wid * 64) * 16;
      __builtin_amdgcn_global_load_lds(
          (const __attribute__((address_space(1))) u32*)src,
          (__attribute__((address_space(3))) u32*)dst, 16, 0, 0);
    }
  };

  auto rdA = [&](int buf, int mh, int m, int ks) -> bf16x8 {
    int s = wm * 64 + m * 16 + rl;
    int off = buf * 65536 + mh * 16384 + s * 128 + (((ks * 32 + kg * 8) * 2) ^ ((s & 7) << 4));
    return *(const bf16x8*)(lds + off);
  };
  auto rdB = [&](int buf, int nh, int n, int ks) -> bf16x8 {
    int s = wn * 32 + n * 16 + rl;
    int off = buf * 65536 + 32768 + nh * 16384 + s * 128 + (((ks * 32 + kg * 8) * 2) ^ ((s & 7) << 4));
    return *(const bf16x8*)(lds + off);
  };

#define GBAR asm volatile("s_barrier" ::: "memory")
#define VMW4 asm volatile("s_waitcnt vmcnt(4)" ::: "memory")

#define PHASE(BUF, MH, NH, STAGECODE, DOVM) do {                               \
    bf16x8 af_[4][2], bf_[2][2];                                               \
    _Pragma("unroll") for (int m_ = 0; m_ < 4; ++m_)                           \
      _Pragma("unroll") for (int k_ = 0; k_ < 2; ++k_)                         \
        af_[m_][k_] = rdA(BUF, MH, m_, k_);                                    \
    _Pragma("unroll") for (int n_ = 0; n_ < 2; ++n_)                           \
      _Pragma("unroll") for (int k_ = 0; k_ < 2; ++k_)                         \
        bf_[n_][k_] = rdB(BUF, NH, n_, k_);                                    \
    STAGECODE;                                                                 \
    if (DOVM) VMW4;                                                            \
    GBAR;                                                                      \
    __builtin_amdgcn_s_setprio(1);                                             \
    _Pragma("unroll") for (int m_ = 0; m_ < 4; ++m_)                           \
      _Pragma("unroll") for (int n_ = 0; n_ < 2; ++n_) {                       \
        acc[(MH)*4+m_][(NH)*2+n_] = __builtin_amdgcn_mfma_f32_16x16x32_bf16(   \
            af_[m_][0], bf_[n_][0], acc[(MH)*4+m_][(NH)*2+n_], 0, 0, 0);       \
        acc[(MH)*4+m_][(NH)*2+n_] = __builtin_amdgcn_mfma_f32_16x16x32_bf16(   \
            af_[m_][1], bf_[n_][1], acc[(MH)*4+m_][(NH)*2+n_], 0, 0, 0);       \
      }                                                                        \
    __builtin_amdgcn_s_setprio(0);                                             \
    GBAR;                                                                      \
  } while (0)

  stageA(0, 0, 0); stageB(0, 0, 0); stageA(0, 1, 0); stageB(0, 1, 0);
  stageA(1, 0, 1); stageB(1, 0, 1);
  VMW4; GBAR;

  for (int i = 0; i < (NT >> 1); ++i) {
    const int T1 = 2 * i + 1;
    int T2 = 2 * i + 2; if (T2 >= NT) T2 -= NT;
    int T3 = 2 * i + 3; if (T3 >= NT) T3 -= NT;
    PHASE(0, 0, 0, stageA(1, 1, T1), 0);
    PHASE(0, 0, 1, stageB(1, 1, T1), 0);
    PHASE(0, 1, 0, stageA(0, 0, T2), 0);
    PHASE(0, 1, 1, stageB(0, 0, T2), 1);
    PHASE(1, 0, 0, stageA(0, 1, T2), 0);
    PHASE(1, 0, 1, stageB(0, 1, T2), 0);
    PHASE(1, 1, 0, stageA(1, 0, T3), 0);
    PHASE(1, 1, 1, stageB(1, 0, T3), 1);
  }
#undef PHASE
#undef GBAR
#undef VMW4

  #pragma unroll
  for (int M = 0; M < 8; ++M) {
    #pragma unroll
    for (int N2 = 0; N2 < 4; ++N2) {
      const int col = col0 + wn * 64 + N2 * 16 + rl;
      const float bs = bias ? bias[col] : 0.f;
      #pragma unroll
      for (int q = 0; q < 4; ++q) {
        const int row = row0 + wm * 128 + M * 16 + kg * 4 + q;
        float v = (acc[M][N2][q] + bs) * sc;
        if (relu) v = fmaxf(v, 0.f);
        if (outF) outF[(size_t)row * ldc + col] = v;
        if (outB) outB[(size_t)row * ldc + col] = pack1bf(v);
      }
    }
  }
}

// ---------- MFMA attention, 2-pass streamed, no-max softmax, V^T in LDS ----------
// Block = (b,h), 512 threads (8 waves), wave owns row-tiles {w,15-w,16+w,31-w}.
// QK projection is PRE-SCALED by sqrt(1/8) in the GEMM epilogue, so the MFMA
// dot product directly yields s = q.k/8 (no per-element scale here).
__global__ __attribute__((amdgpu_flat_work_group_size(512, 512)))
           __attribute__((amdgpu_waves_per_eu(1, 2)))
void attn_mfma(
    const u16* __restrict__ qk, const u16* __restrict__ vbuf,
    const float* __restrict__ gam, u16* __restrict__ out,
    int mask_excl, int zero_pad)
{
  __shared__ __align__(16) u8 kSb[65536];  // K/Q rows [512][64] bf16, byte ^= (row&7)<<4
  __shared__ __align__(16) u8 vTb[65536];  // V^T [64 d][512 k] bf16, byte ^= ((d&7)^((d>>3)&7))<<4
  __shared__ __align__(16) u8 pChb[8192];  // per-wave 1KB P chunk buffers

  const int t    = threadIdx.x;
  const int lane = t & 63, wid = t >> 6;
  const int ql   = lane & 15, g = lane >> 4;
  const int bh   = blockIdx.x, b = bh >> 3, h = bh & 7;
  const size_t base = (size_t)b * SS * DDIM + (size_t)h * 64;

  float gv = gam[h];
  float sp = (gv > 0.f) ? (gv + log1pf(__expf(-gv))) : log1pf(__expf(gv));
  const float gamma = -sp;

  // ---- stage K/Q (pre-scaled by sqrt(1/8)) ----
  for (int it = 0; it < 8; ++it) {
    int idx = it * 512 + t;
    int j = idx >> 3, u = idx & 7;
    uint4 w = *(const uint4*)(qk + base + (size_t)j * DDIM + u * 8);
    *(uint4*)(kSb + ((j * 128 + u * 16) ^ ((j & 7) << 4))) = w;
  }
  // ---- stage V^T (static dd; (dd^u) write-swizzle) ----
  for (int it = 0; it < 8; ++it) {
    int idx = it * 512 + t;
    int j = idx >> 3, u = idx & 7;
    union { uint4 v4; u16 s[8]; } uu;
    uu.v4 = *(const uint4*)(vbuf + base + (size_t)j * DDIM + u * 8);
    #pragma unroll
    for (int dd = 0; dd < 8; ++dd) {
      int d = u * 8 + dd;
      *(u16*)(vTb + d * 1024 + ((2 * j) ^ ((dd ^ u) << 4))) = uu.s[dd];
    }
  }
  __syncthreads();

  bool vm[4];
  #pragma unroll
  for (int rg = 0; rg < 4; ++rg) {
    int kl = 4 * g + rg;
    vm[rg] = mask_excl ? (kl < ql) : (kl <= ql);
  }

  u8* pB = pChb + wid * 1024;
  const int swp = (ql & 7) << 4;   // r10: 8-way spread (was 4-way) — bijective in 1KB

  int vbase[4], vsw[4];
  #pragma unroll
  for (int n = 0; n < 4; ++n) {
    int d = n * 16 + ql;
    vbase[n] = d * 1024;
    vsw[n]   = ((d & 7) ^ ((d >> 3) & 7)) << 4;
  }

  #pragma unroll
  for (int ri = 0; ri < 4; ++ri) {
    int r0_ = (ri == 0) ? wid : (ri == 1) ? (15 - wid) : (ri == 2) ? (16 + wid) : (31 - wid);
    const int rs = __builtin_amdgcn_readfirstlane(r0_);
    const int i0 = rs * 16;

    const int qrow = i0 + ql;
    const int qsw  = (qrow & 7) << 4;
    bf16x8 qf0 = *(const bf16x8*)(kSb + ((qrow * 128      + g * 16) ^ qsw));
    bf16x8 qf1 = *(const bf16x8*)(kSb + ((qrow * 128 + 64 + g * 16) ^ qsw));

    // ---- pass 1: S1 only (no max tracking) ----
    float S1l = 0.f;
    #pragma unroll
    for (int kt = 0; kt < 32; ++kt) {
      if (kt <= rs) {
        const bool dg = (kt == rs);
        const int krow = kt * 16 + ql;
        const int ksw  = (krow & 7) << 4;
        bf16x8 ka0 = *(const bf16x8*)(kSb + ((krow * 128      + g * 16) ^ ksw));
        bf16x8 ka1 = *(const bf16x8*)(kSb + ((krow * 128 + 64 + g * 16) ^ ksw));
        f32x4 dv = {};
        dv = __builtin_amdgcn_mfma_f32_16x16x32_bf16(ka0, qf0, dv, 0, 0, 0);
        dv = __builtin_amdgcn_mfma_f32_16x16x32_bf16(ka1, qf1, dv, 0, 0, 0);
        float e0 = (!dg || vm[0]) ? expc(dv[0]) : 0.f;
        float e1 = (!dg || vm[1]) ? expc(dv[1]) : 0.f;
        float e2 = (!dg || vm[2]) ? expc(dv[2]) : 0.f;
        float e3 = (!dg || vm[3]) ? expc(dv[3]) : 0.f;
        S1l += (e0 + e1) + (e2 + e3);
      }
    }
    const float S1   = redsum2(S1l);
    const float inv1 = (S1 > 0.f) ? (1.f / S1) : 0.f;

    // ---- pass 2: streamed recompute -> cumsum -> rescore -> PV ----
    f32x4 oacc[4] = {};
    float cbase = 0.f, S2l = 0.f;
    const float qlf = (float)(i0 + ql);

    auto subkt = [&](int kt, bool dg, u32& wA, u32& wB) {
      const int krow = kt * 16 + ql;
      const int ksw  = (krow & 7) << 4;
      bf16x8 ka0 = *(const bf16x8*)(kSb + ((krow * 128      + g * 16) ^ ksw));
      bf16x8 ka1 = *(const bf16x8*)(kSb + ((krow * 128 + 64 + g * 16) ^ ksw));
      f32x4 dv = {};
      dv = __builtin_amdgcn_mfma_f32_16x16x32_bf16(ka0, qf0, dv, 0, 0, 0);
      dv = __builtin_amdgcn_mfma_f32_16x16x32_bf16(ka1, qf1, dv, 0, 0, 0);
      const bool v0 = !dg || vm[0], v1 = !dg || vm[1];
      const bool v2 = !dg || vm[2], v3 = !dg || vm[3];
      float e0 = v0 ? expc(dv[0]) : 0.f;
      float e1 = v1 ? expc(dv[1]) : 0.f;
      float e2 = v2 ? expc(dv[2]) : 0.f;
      float e3 = v3 ? expc(dv[3]) : 0.f;
      float p0 = e0, p1 = p0 + e1, p2 = p1 + e2, p3 = p2 + e3;
      float a16 = __shfl_up(p3, 16, 64);
      float a32 = __shfl_up(p3, 32, 64);
      float a48 = __shfl_up(p3, 48, 64);
      float gp = (g >= 1 ? a16 : 0.f) + (g >= 2 ? a32 : 0.f) + (g >= 3 ? a48 : 0.f);
      float tt = __shfl(gp + p3, ql + 48, 64);
      const float pbase = cbase + gp;
      const float pf = qlf - (float)(kt * 16 + 4 * g);
      float ipr[4] = {p0, p1, p2, p3};
      bool  vv[4]  = {v0, v1, v2, v3};
      float sv[4]  = {dv[0], dv[1], dv[2], dv[3]};
      float q2[4];
      #pragma unroll
      for (int rg = 0; rg < 4; ++rg) {
        float rem  = fmaxf((S1 - (pbase + ipr[rg])) * inv1, 0.f);
        float pos  = pf - (float)rg;
        float dist = sqrtf(fmaxf(rem * pos, 0.f));
        float eff  = fmaxf(__expf(gamma * dist), 1e-5f);
        float ee   = vv[rg] ? expc(sv[rg] * eff) : 0.f;
        q2[rg] = ee;
        S2l += ee;
      }
      wA = packbf2(q2[0], q2[1]);
      wB = packbf2(q2[2], q2[3]);
      cbase += tt;
    };

    #pragma unroll
    for (int c = 0; c < 16; ++c) {
      if (2 * c <= rs) {
        u32 w0 = 0, w1 = 0, w2 = 0, w3 = 0;
        subkt(2 * c, (2 * c == rs), w0, w1);
        if (2 * c + 1 <= rs) subkt(2 * c + 1, (2 * c + 1 == rs), w2, w3);
        *(u32*)(pB + ((ql * 64 +      8 * g    ) ^ swp)) = w0;
        *(u32*)(pB + ((ql * 64 +      8 * g + 4) ^ swp)) = w1;
        *(u32*)(pB + ((ql * 64 + 32 + 8 * g    ) ^ swp)) = w2;
        *(u32*)(pB + ((ql * 64 + 32 + 8 * g + 4) ^ swp)) = w3;
        bf16x8 pa = *(const bf16x8*)(pB + ((ql * 64 + 16 * g) ^ swp));
        #pragma unroll
        for (int n = 0; n < 4; ++n) {
          bf16x8 vb = *(const bf16x8*)(vTb + vbase[n] + ((64 * c + 16 * g) ^ vsw[n]));
          oacc[n] = __builtin_amdgcn_mfma_f32_16x16x32_bf16(pa, vb, oacc[n], 0, 0, 0);
        }
      }
    }

    const float S2   = redsum2(S2l);
    const float inv2 = 1.f / fmaxf(S2, 1e-30f);
    float i2[4];
    #pragma unroll
    for (int rg = 0; rg < 4; ++rg) i2[rg] = __shfl(inv2, 4 * g + rg, 64);

    #pragma unroll
    for (int n = 0; n < 4; ++n) {
      #pragma unroll
      for (int rg = 0; rg < 4; ++rg) {
        const int qo = i0 + 4 * g + rg;
        float val = oacc[n][rg] * i2[rg];
        if (zero_pad && qo == 0) val = 0.f;
        out[base + (size_t)qo * DDIM + n * 16 + ql] = pack1bf(val);
      }
    }
  }
}

// ---------- fused residual + LayerNorm: out = LN(a_bf16 + b [+ c]) ----------
__global__ __launch_bounds__(256) void ln_kernel(
    const u16* __restrict__ a, const float* __restrict__ bsrc,
    const float* __restrict__ csrc,
    const float* __restrict__ g, const float* __restrict__ be,
    float* __restrict__ outF, u16* __restrict__ outB)
{
  const int lane = threadIdx.x & 63, w = threadIdx.x >> 6;
  const size_t row = (size_t)blockIdx.x * 4 + w;
  const size_t off8 = row * DDIM + lane * 8;

  uint4 ab = *(const uint4*)(a + off8);
  const u16* ap = (const u16*)&ab;
  float v[8];
  #pragma unroll
  for (int k = 0; k < 8; ++k) v[k] = __uint_as_float(((u32)ap[k]) << 16);

  float4 b0 = *(const float4*)(bsrc + off8);
  float4 b1 = *(const float4*)(bsrc + off8 + 4);
  v[0] += b0.x; v[1] += b0.y; v[2] += b0.z; v[3] += b0.w;
  v[4] += b1.x; v[5] += b1.y; v[6] += b1.z; v[7] += b1.w;
  if (csrc) {
    float4 c0 = *(const float4*)(csrc + off8);
    float4 c1 = *(const float4*)(csrc + off8 + 4);
    v[0] += c0.x; v[1] += c0.y; v[2] += c0.z; v[3] += c0.w;
    v[4] += c1.x; v[5] += c1.y; v[6] += c1.z; v[7] += c1.w;
  }

  float sum = 0.f;
  #pragma unroll
  for (int k = 0; k < 8; ++k) sum += v[k];
  #pragma unroll
  for (int off = 32; off > 0; off >>= 1) sum += __shfl_xor(sum, off, 64);
  const float mean = sum * (1.f / 512.f);
  float var = 0.f;
  #pragma unroll
  for (int k = 0; k < 8; ++k) { float dd = v[k] - mean; var = fmaf(dd, dd, var); }
  #pragma unroll
  for (int off = 32; off > 0; off >>= 1) var += __shfl_xor(var, off, 64);
  var *= (1.f / 512.f);
  const float inv = rsqrtf(var + 1e-5f);

  float4 g0 = *(const float4*)(g + lane * 8);
  float4 g1 = *(const float4*)(g + lane * 8 + 4);
  float4 e0 = *(const float4*)(be + lane * 8);
  float4 e1 = *(const float4*)(be + lane * 8 + 4);
  float gv[8] = {g0.x, g0.y, g0.z, g0.w, g1.x, g1.y, g1.z, g1.w};
  float ev[8] = {e0.x, e0.y, e0.z, e0.w, e1.x, e1.y, e1.z, e1.w};
  float o[8];
  #pragma unroll
  for (int k = 0; k < 8; ++k) o[k] = (v[k] - mean) * inv * gv[k] + ev[k];

  if (outF) {
    float4 f0 = {o[0], o[1], o[2], o[3]};
    float4 f1 = {o[4], o[5], o[6], o[7]};
    *(float4*)(outF + off8)     = f0;
    *(float4*)(outF + off8 + 4) = f1;
  }
  if (outB) {
    uint4 p;
    p.x = packbf2(o[0], o[1]); p.y = packbf2(o[2], o[3]);
    p.z = packbf2(o[4], o[5]); p.w = packbf2(o[6], o[7]);
    *(uint4*)(outB + off8) = p;
  }
}

// ---------- orchestration ----------
extern "C" void kernel_launch(void* const* d_in, const int* in_sizes, int n_in,
                              void* d_out, int out_size, void* d_ws, size_t ws_size,
                              hipStream_t stream) {
  const float* qe  = (const float*)d_in[0];
  const float* qa  = (const float*)d_in[1];
  const float* Wk  = (const float*)d_in[2];
  const float* bk  = (const float*)d_in[3];
  const float* Wv  = (const float*)d_in[4];
  const float* bv  = (const float*)d_in[5];
  const float* Wo  = (const float*)d_in[6];
  const float* bo  = (const float*)d_in[7];
  const float* gm  = (const float*)d_in[8];
  const float* l1g = (const float*)d_in[9];
  const float* l1b = (const float*)d_in[10];
  const float* W1  = (const float*)d_in[11];
  const float* b1  = (const float*)d_in[12];
  const float* W2  = (const float*)d_in[13];
  const float* b2  = (const float*)d_in[14];
  const float* l2g = (const float*)d_in[15];
  const float* l2b = (const float*)d_in[16];

  char* ws = (char*)d_ws;
  u16* WT = (u16*)ws;                              // 17.3 MB packed weights
  u16* A0 = (u16*)(ws + ((size_t)18  << 20));      // 16 MiB bf16 act slots
  u16* A1 = (u16*)(ws + ((size_t)34  << 20));
  u16* A2 = (u16*)(ws + ((size_t)50  << 20));
  u16* A3 = (u16*)(ws + ((size_t)66  << 20));
  float* F0 = (float*)(ws + ((size_t)82  << 20));  // 32 MiB f32 GEMM-out slot
  float* PW2 = (float*)(ws + ((size_t)114 << 20)); // 32 MiB W2 split-K partial
  u16* Amid = (u16*)(ws + ((size_t)146 << 20));    // 64 MiB FFN mid
  float* PWo = (float*)Amid;                        // Wo split-K partial (disjoint lifetime)

  u16* WkT = WT;                    // [L][512][512]
  u16* WvT = WT + (size_t)3 * 262144;
  u16* WoT = WT + (size_t)6 * 262144;
  u16* W1T = WT + (size_t)9 * 262144;              // [L][2048][512]
  u16* W2T = W1T + (size_t)3 * 1048576;            // [L][512][2048]

  pack_w_t<<<dim3(8, 8, 3),  256, 0, stream>>>(Wk, WkT, 512, 512);
  pack_w_t<<<dim3(8, 8, 3),  256, 0, stream>>>(Wv, WvT, 512, 512);
  pack_w_t<<<dim3(8, 8, 3),  256, 0, stream>>>(Wo, WoT, 512, 512);
  pack_w_t<<<dim3(32, 8, 3), 256, 0, stream>>>(W1, W1T, 512, 2048);
  pack_w_t<<<dim3(8, 32, 3), 256, 0, stream>>>(W2, W2T, 2048, 512);
  pack_flat<<<4096, 256, 0, stream>>>(qa, A0);
  pack_flat<<<4096, 256, 0, stream>>>(qe, A1);

  const float SQ = 0.35355339059327373f;  // sqrt(1/8): folds attn scale into QK proj

  auto g8 = [&](const u16* Aa, const u16* Ab, int lda,
                const u16* Ba, const u16* Bb, int ldb,
                const float* ba, const float* bb,
                float* oFa, float* oFb, u16* oBa, u16* oBb,
                int ldc, int M, int N, int Kz, int relu, int nz,
                float sca, float scb) {
    gemm8<<<dim3(N / 256, M / 256, nz), 512, 0, stream>>>(
        Aa, Ab, lda, Ba, Bb, ldb, ba, bb, oFa, oFb, oBa, oBb, ldc, Kz, relu,
        sca, scb);
  };

  // qbf: bf16 query (attn input AND ln1 residual); vbf: bf16 values
  // x1B: ln1 bf16 out (FFN input + ln2 residual); y2B/y2F: ln2 outs
  auto layer = [&](int li, const u16* qbf, const u16* vbf,
                   int excl, int zp, int pos,
                   u16* x1B, u16* y2B, float* y2F) {
    const float* bk_l = bk + (size_t)li * DDIM;
    const float* bv_l = bv + (size_t)li * DDIM;
    const float* bo_l = bo + (size_t)li * DDIM;
    const float* gm_l = gm + (size_t)li * HH;
    const float* g1   = l1g + (size_t)li * DDIM;
    const float* be1  = l1b + (size_t)li * DDIM;
    const float* g2   = l2g + (size_t)li * DDIM;
    const float* be2  = l2b + (size_t)li * DDIM;
    const float* b1_l = b1 + (size_t)li * DFFN;
    const float* b2_l = b2 + (size_t)li * DDIM;
    const u16* WkT_l = WkT + (size_t)li * 262144;
    const u16* WvT_l = WvT + (size_t)li * 262144;
    const u16* WoT_l = WoT + (size_t)li * 262144;
    const u16* W1T_l = W1T + (size_t)li * 1048576;
    const u16* W2T_l = W2T + (size_t)li * 1048576;

    // fused qk + v projections (z-batched); QK pre-scaled by sqrt(1/8)
    g8(qbf, vbf, 512, WkT_l, WvT_l, 512, bk_l, bv_l,
       nullptr, nullptr, A2, A3, 512, MR, 512, 512, 0, 2, SQ, 1.f);
    attn_mfma<<<BB * HH, 512, 0, stream>>>(A2, A3, gm_l, A3, excl, zp);
    // Wo: split-K (z0: k<256 +bias -> F0; z1: k>=256 -> PWo)
    g8(A3, A3 + 256, 512, WoT_l, WoT_l + 256, 512, bo_l, nullptr,
       F0, PWo, nullptr, nullptr, 512, MR, 512, 256, 0, 2, 1.f, 1.f);
    ln_kernel<<<MR / 4, 256, 0, stream>>>(qbf, F0, PWo, g1, be1, nullptr, x1B);
    if (pos) {
      g8(x1B, nullptr, 512, W1T_l, nullptr, 512, b1_l, nullptr,
         nullptr, nullptr, Amid, nullptr, 2048, MR, 2048, 512, 1, 1, 1.f, 1.f);
      g8(Amid, Amid + 1024, 2048, W2T_l, W2T_l + 1024, 2048, b2_l, nullptr,
         F0, PW2, nullptr, nullptr, 512, MR, 512, 1024, 0, 2, 1.f, 1.f);
      ln_kernel<<<MR / 4, 256, 0, stream>>>(x1B, F0, PW2, g2, be2, y2F, y2B);
    }
  };

  // layer 0: self-attn on qa, incl mask, FFN -> y1 bf16 in A0
  layer(0, A0, A0, 0, 0, 1, A2, A0, nullptr);
  // layer 1: self-attn on qe, incl mask, no FFN -> x1 bf16 in A1 (in-place LN)
  layer(1, A1, A1, 0, 0, 0, A1, nullptr, nullptr);
  // layer 2: cross-attn (q = x1, values = y1), strict mask, zero_pad, FFN -> d_out f32
  layer(2, A1, A0, 1, 1, 1, A1, nullptr, (float*)d_out);
}